// Round 1
// baseline (550.470 us; speedup 1.0000x reference)
//
#include <hip/hip_runtime.h>
#include <stdint.h>

#define N_NODES 100000
#define N_EDGES 3200000
#define F_IN 256
#define HID 16
#define NCLS 7

// ---------------- edge dtype detection (int64 vs int32) -------------------
__global__ void detect_kernel(const uint32_t* edge_raw, int* flag) {
    __shared__ int s_any;
    if (threadIdx.x == 0) s_any = 0;
    __syncthreads();
    uint32_t v = 0;
    for (int i = 0; i < 16; ++i) {
        int idx = threadIdx.x * 16 + i;   // 0..4095 -> words up to 8191, in-bounds either way
        v |= edge_raw[2 * idx + 1];
    }
    if (v) atomicOr(&s_any, 1);
    __syncthreads();
    if (threadIdx.x == 0) *flag = (s_any == 0) ? 1 : 0;  // 1 => int64 layout
}

// ---------------- edge conversion + degree histogram ----------------------
__global__ void prep_kernel(const void* edge_raw, const int* flag,
                            int* src32, int* dst32, int* deg) {
    int e = blockIdx.x * blockDim.x + threadIdx.x;
    if (e >= N_EDGES) return;
    int is64 = *flag;
    int s, d;
    if (is64) {
        const long long* p = (const long long*)edge_raw;
        s = (int)p[e];
        d = (int)p[N_EDGES + e];
    } else {
        const int* p = (const int*)edge_raw;
        s = p[e];
        d = p[N_EDGES + e];
    }
    src32[e] = s;
    dst32[e] = d;
    atomicAdd(&deg[d], 1);
}

// ---------------- prefix scan (3 phases) ----------------------------------
__global__ void scan1_kernel(const int* deg, int* row_start, float* dinv, int* bsum) {
    __shared__ int sh[256];
    int t = threadIdx.x;
    int base = blockIdx.x * 1024 + t * 4;
    int v0 = 0, v1 = 0, v2 = 0, v3 = 0;
    if (base + 0 < N_NODES) v0 = deg[base + 0];
    if (base + 1 < N_NODES) v1 = deg[base + 1];
    if (base + 2 < N_NODES) v2 = deg[base + 2];
    if (base + 3 < N_NODES) v3 = deg[base + 3];
    int tsum = v0 + v1 + v2 + v3;
    sh[t] = tsum;
    __syncthreads();
    for (int off = 1; off < 256; off <<= 1) {
        int add = (t >= off) ? sh[t - off] : 0;
        __syncthreads();
        sh[t] += add;
        __syncthreads();
    }
    int r = sh[t] - tsum;  // exclusive prefix of this thread's chunk
    if (base + 0 < N_NODES) { row_start[base + 0] = r; dinv[base + 0] = rsqrtf((float)(v0 + 1)); } r += v0;
    if (base + 1 < N_NODES) { row_start[base + 1] = r; dinv[base + 1] = rsqrtf((float)(v1 + 1)); } r += v1;
    if (base + 2 < N_NODES) { row_start[base + 2] = r; dinv[base + 2] = rsqrtf((float)(v2 + 1)); } r += v2;
    if (base + 3 < N_NODES) { row_start[base + 3] = r; dinv[base + 3] = rsqrtf((float)(v3 + 1)); }
    if (t == 255) bsum[blockIdx.x] = sh[255];
}

__global__ void scan2_kernel(int* bsum, int nb) {
    __shared__ int sh[128];
    int t = threadIdx.x;
    int v = (t < nb) ? bsum[t] : 0;
    sh[t] = v;
    __syncthreads();
    for (int off = 1; off < 128; off <<= 1) {
        int add = (t >= off) ? sh[t - off] : 0;
        __syncthreads();
        sh[t] += add;
        __syncthreads();
    }
    if (t < nb) bsum[t] = sh[t] - v;
}

__global__ void scan3_kernel(int* row_start, int* cursor, const int* bsum) {
    int t = threadIdx.x;
    int base = blockIdx.x * 1024 + t * 4;
    int add = bsum[blockIdx.x];
#pragma unroll
    for (int k = 0; k < 4; ++k) {
        int i = base + k;
        if (i < N_NODES) {
            int rv = row_start[i] + add;
            row_start[i] = rv;
            cursor[i] = rv;
        }
    }
    if (blockIdx.x == 0 && t == 0) row_start[N_NODES] = N_EDGES;
}

// ---------------- scatter into CSR ----------------------------------------
__global__ void scatter_kernel(const int* src32, const int* dst32, int* cursor, int* ssort) {
    int e = blockIdx.x * blockDim.x + threadIdx.x;
    if (e >= N_EDGES) return;
    int d = dst32[e];
    int pos = atomicAdd(&cursor[d], 1);
    ssort[pos] = src32[e];
}

// ---------------- GEMM1: y = dinv * (x @ W1) -------------------------------
#define XS_STRIDE 260
__global__ __launch_bounds__(256) void gemm1_kernel(const float* __restrict__ x,
                                                    const float* __restrict__ W1,
                                                    const float* __restrict__ dinv,
                                                    float* __restrict__ y) {
    __shared__ float xs[32 * XS_STRIDE];
    __shared__ float wl[F_IN * HID];
    int t = threadIdx.x;
    // load W1 (4096 floats) as float4
    for (int i = t; i < F_IN * HID / 4; i += 256) {
        ((float4*)wl)[i] = ((const float4*)W1)[i];
    }
    int v0 = blockIdx.x * 32;
    // stage 32 rows of x
    for (int c = t; c < 32 * 64; c += 256) {
        int r = c >> 6;
        int j4 = c & 63;
        float4 val = ((const float4*)(x + (size_t)(v0 + r) * F_IN))[j4];
        *((float4*)(xs + r * XS_STRIDE + j4 * 4)) = val;
    }
    __syncthreads();
    int n = t >> 3;          // node within tile (0..31)
    int k0 = (t & 7) * 2;    // feature pair
    const float* xrow = xs + n * XS_STRIDE;
    float a0 = 0.f, a1 = 0.f;
#pragma unroll 4
    for (int j = 0; j < F_IN; j += 4) {
        float4 xv = *((const float4*)(xrow + j));
        float2 w0 = *((const float2*)(wl + (j + 0) * HID + k0));
        float2 w1 = *((const float2*)(wl + (j + 1) * HID + k0));
        float2 w2 = *((const float2*)(wl + (j + 2) * HID + k0));
        float2 w3 = *((const float2*)(wl + (j + 3) * HID + k0));
        a0 += xv.x * w0.x + xv.y * w1.x + xv.z * w2.x + xv.w * w3.x;
        a1 += xv.x * w0.y + xv.y * w1.y + xv.z * w2.y + xv.w * w3.y;
    }
    int v = v0 + n;
    float dv = dinv[v];
    float2 o2;
    o2.x = a0 * dv;
    o2.y = a1 * dv;
    *((float2*)(y + (size_t)v * HID + k0)) = o2;
}

// ---------------- aggregation: h = relu(dinv*(sum_in y + y_self) + b) ------
__global__ __launch_bounds__(256) void agg_kernel(const float* __restrict__ y,
                                                  const float* __restrict__ dinv,
                                                  const float* __restrict__ bias,
                                                  const int* __restrict__ row_start,
                                                  const int* __restrict__ ssort,
                                                  float* __restrict__ hout) {
    int wid = (blockIdx.x * blockDim.x + threadIdx.x) >> 6;  // one wave per node
    int lane = threadIdx.x & 63;
    int v = wid;
    if (v >= N_NODES) return;
    int start = row_start[v];
    int end = row_start[v + 1];
    int q = lane & 3;    // feature quad
    int eg = lane >> 2;  // edge slot (0..15)
    float4 acc = make_float4(0.f, 0.f, 0.f, 0.f);
    for (int base = start; base < end; base += 16) {
        int e = base + eg;
        if (e < end) {
            int s = ssort[e];
            float4 yv = *((const float4*)(y + (size_t)s * HID + q * 4));
            acc.x += yv.x; acc.y += yv.y; acc.z += yv.z; acc.w += yv.w;
        }
    }
#pragma unroll
    for (int m = 4; m < 64; m <<= 1) {
        acc.x += __shfl_xor(acc.x, m);
        acc.y += __shfl_xor(acc.y, m);
        acc.z += __shfl_xor(acc.z, m);
        acc.w += __shfl_xor(acc.w, m);
    }
    if (lane < 4) {
        float4 self = *((const float4*)(y + (size_t)v * HID + lane * 4));
        float dv = dinv[v];
        float4 bv = *((const float4*)(bias + lane * 4));
        float4 r;
        r.x = fmaxf(dv * (acc.x + self.x) + bv.x, 0.f);
        r.y = fmaxf(dv * (acc.y + self.y) + bv.y, 0.f);
        r.z = fmaxf(dv * (acc.z + self.z) + bv.z, 0.f);
        r.w = fmaxf(dv * (acc.w + self.w) + bv.w, 0.f);
        *((float4*)(hout + (size_t)v * HID + lane * 4)) = r;
    }
}

// ---------------- GEMM2: y = dinv * (h @ W2) -------------------------------
__global__ __launch_bounds__(256) void gemm2_kernel(const float* __restrict__ h,
                                                    const float* __restrict__ W2,
                                                    const float* __restrict__ dinv,
                                                    float* __restrict__ y) {
    __shared__ float wl[HID * HID];
    int t = threadIdx.x;
    if (t < 64) ((float4*)wl)[t] = ((const float4*)W2)[t];
    __syncthreads();
    int v = blockIdx.x * blockDim.x + t;
    if (v >= N_NODES) return;
    float hr[16];
    const float4* hp = (const float4*)(h + (size_t)v * HID);
#pragma unroll
    for (int r = 0; r < 4; ++r) {
        float4 hv = hp[r];
        hr[4 * r + 0] = hv.x; hr[4 * r + 1] = hv.y; hr[4 * r + 2] = hv.z; hr[4 * r + 3] = hv.w;
    }
    float acc[16];
#pragma unroll
    for (int k = 0; k < 16; ++k) acc[k] = 0.f;
#pragma unroll
    for (int j = 0; j < 16; ++j) {
        float hv = hr[j];
        const float4* wr = (const float4*)(wl + j * 16);
        float4 w0 = wr[0], w1 = wr[1], w2 = wr[2], w3 = wr[3];
        acc[0] += hv * w0.x;  acc[1] += hv * w0.y;  acc[2] += hv * w0.z;  acc[3] += hv * w0.w;
        acc[4] += hv * w1.x;  acc[5] += hv * w1.y;  acc[6] += hv * w1.z;  acc[7] += hv * w1.w;
        acc[8] += hv * w2.x;  acc[9] += hv * w2.y;  acc[10] += hv * w2.z; acc[11] += hv * w2.w;
        acc[12] += hv * w3.x; acc[13] += hv * w3.y; acc[14] += hv * w3.z; acc[15] += hv * w3.w;
    }
    float dv = dinv[v];
    float4* yp = (float4*)(y + (size_t)v * HID);
#pragma unroll
    for (int r = 0; r < 4; ++r) {
        float4 o;
        o.x = acc[4 * r + 0] * dv; o.y = acc[4 * r + 1] * dv;
        o.z = acc[4 * r + 2] * dv; o.w = acc[4 * r + 3] * dv;
        yp[r] = o;
    }
}

// ---------------- output layer + log_softmax -------------------------------
__global__ __launch_bounds__(256) void out_kernel(const float* __restrict__ h,
                                                  const float* __restrict__ Wout,
                                                  const float* __restrict__ bout,
                                                  float* __restrict__ out) {
    __shared__ float wl[HID * NCLS];
    __shared__ float bl[NCLS];
    int t = threadIdx.x;
    if (t < HID * NCLS) wl[t] = Wout[t];
    if (t < NCLS) bl[t] = bout[t];
    __syncthreads();
    int v = blockIdx.x * blockDim.x + t;
    if (v >= N_NODES) return;
    float hr[16];
    const float4* hp = (const float4*)(h + (size_t)v * HID);
#pragma unroll
    for (int r = 0; r < 4; ++r) {
        float4 hv = hp[r];
        hr[4 * r + 0] = hv.x; hr[4 * r + 1] = hv.y; hr[4 * r + 2] = hv.z; hr[4 * r + 3] = hv.w;
    }
    float lg[NCLS];
#pragma unroll
    for (int c = 0; c < NCLS; ++c) {
        float a = bl[c];
#pragma unroll
        for (int j = 0; j < HID; ++j) a += hr[j] * wl[j * NCLS + c];
        lg[c] = a;
    }
    float m = lg[0];
#pragma unroll
    for (int c = 1; c < NCLS; ++c) m = fmaxf(m, lg[c]);
    float ssum = 0.f;
#pragma unroll
    for (int c = 0; c < NCLS; ++c) ssum += expf(lg[c] - m);
    float lse = m + logf(ssum);
#pragma unroll
    for (int c = 0; c < NCLS; ++c) out[(size_t)v * NCLS + c] = lg[c] - lse;
}

extern "C" void kernel_launch(void* const* d_in, const int* in_sizes, int n_in,
                              void* d_out, int out_size, void* d_ws, size_t ws_size,
                              hipStream_t stream) {
    const float* x    = (const float*)d_in[0];
    const void*  edge = d_in[1];
    const float* W1   = (const float*)d_in[2];
    const float* b1   = (const float*)d_in[3];
    const float* W2   = (const float*)d_in[4];
    const float* b2   = (const float*)d_in[5];
    const float* Wout = (const float*)d_in[6];
    const float* bout = (const float*)d_in[7];
    float* out = (float*)d_out;
    char* ws = (char*)d_ws;

    auto al = [](size_t v) { return (v + 255) & ~(size_t)255; };
    size_t o = 0;
    int*   flag      = (int*)(ws + o);   o = al(o + 4);
    int*   deg       = (int*)(ws + o);   o = al(o + (size_t)N_NODES * 4);
    int*   row_start = (int*)(ws + o);   o = al(o + (size_t)(N_NODES + 1) * 4);
    int*   cursor    = (int*)(ws + o);   o = al(o + (size_t)N_NODES * 4);
    float* dinv      = (float*)(ws + o); o = al(o + (size_t)N_NODES * 4);
    int*   bsum      = (int*)(ws + o);   o = al(o + 512);
    int*   src32     = (int*)(ws + o);   o = al(o + (size_t)N_EDGES * 4);
    int*   dst32     = (int*)(ws + o);   o = al(o + (size_t)N_EDGES * 4);
    int*   ssort     = (int*)(ws + o);   o = al(o + (size_t)N_EDGES * 4);
    float* ybuf      = (float*)(ws + o); o = al(o + (size_t)N_NODES * HID * 4);
    float* hbuf      = (float*)(ws + o); o = al(o + (size_t)N_NODES * HID * 4);

    hipMemsetAsync(deg, 0, (size_t)N_NODES * 4, stream);
    detect_kernel<<<1, 256, 0, stream>>>((const uint32_t*)edge, flag);
    prep_kernel<<<N_EDGES / 256, 256, 0, stream>>>(edge, flag, src32, dst32, deg);
    scan1_kernel<<<98, 256, 0, stream>>>(deg, row_start, dinv, bsum);
    scan2_kernel<<<1, 128, 0, stream>>>(bsum, 98);
    scan3_kernel<<<98, 256, 0, stream>>>(row_start, cursor, bsum);
    scatter_kernel<<<N_EDGES / 256, 256, 0, stream>>>(src32, dst32, cursor, ssort);
    gemm1_kernel<<<N_NODES / 32, 256, 0, stream>>>(x, W1, dinv, ybuf);
    agg_kernel<<<(N_NODES * 64) / 256, 256, 0, stream>>>(ybuf, dinv, b1, row_start, ssort, hbuf);
    gemm2_kernel<<<(N_NODES + 255) / 256, 256, 0, stream>>>(hbuf, W2, dinv, ybuf);
    agg_kernel<<<(N_NODES * 64) / 256, 256, 0, stream>>>(ybuf, dinv, b2, row_start, ssort, hbuf);
    out_kernel<<<(N_NODES + 255) / 256, 256, 0, stream>>>(hbuf, Wout, bout, out);
}

// Round 2
// 237.523 us; speedup vs baseline: 2.3175x; 2.3175x over previous
//
#include <hip/hip_runtime.h>
#include <stdint.h>

#define N_NODES 100000
#define N_EDGES 3200000
#define F_IN 256
#define HID 16
#define NCLS 7

#define NBUCK 196        // ceil(100000 / 512) buckets of 512 nodes (dst >> 9)
#define BCAP 20480       // capacity per bucket (avg 16384, sigma ~128 -> 32 sigma headroom)
#define EPB 4096         // edges per block in bucket_kernel (16 per thread)

// ---------------- edge dtype detection (int64 vs int32) -------------------
__global__ void detect_kernel(const uint32_t* edge_raw, int* flag) {
    __shared__ int s_any;
    if (threadIdx.x == 0) s_any = 0;
    __syncthreads();
    uint32_t v = 0;
    for (int i = 0; i < 16; ++i) {
        int idx = threadIdx.x * 16 + i;   // words up to 8191, in-bounds either way
        v |= edge_raw[2 * idx + 1];
    }
    if (v) atomicOr(&s_any, 1);
    __syncthreads();
    if (threadIdx.x == 0) *flag = (s_any == 0) ? 1 : 0;  // 1 => int64 layout
}

// ---------------- pass 1: bin edges into 196 dst-buckets -------------------
__global__ __launch_bounds__(256) void bucket_kernel(const void* edge_raw, const int* flag,
                                                     int* gcount, uint32_t* temp) {
    __shared__ int cnt[NBUCK];
    __shared__ int base[NBUCK];
    int t = threadIdx.x;
    if (t < NBUCK) cnt[t] = 0;
    __syncthreads();
    int is64 = *flag;
    int e0 = blockIdx.x * EPB;
    uint32_t val[16];
    int rb[16];  // (bucket << 16) | local_rank, or -1
#pragma unroll
    for (int k = 0; k < 16; ++k) {
        int e = e0 + k * 256 + t;
        if (e < N_EDGES) {
            int s, d;
            if (is64) {
                const long long* p = (const long long*)edge_raw;
                s = (int)p[e]; d = (int)p[N_EDGES + e];
            } else {
                const int* p = (const int*)edge_raw;
                s = p[e]; d = p[N_EDGES + e];
            }
            int b = d >> 9;
            val[k] = ((uint32_t)s << 9) | (uint32_t)(d & 511);
            int r = atomicAdd(&cnt[b], 1);
            rb[k] = (b << 16) | r;
        } else {
            rb[k] = -1;
        }
    }
    __syncthreads();
    if (t < NBUCK) base[t] = atomicAdd(&gcount[t], cnt[t]);
    __syncthreads();
#pragma unroll
    for (int k = 0; k < 16; ++k) {
        if (rb[k] >= 0) {
            int b = rb[k] >> 16;
            int pos = base[b] + (rb[k] & 0xFFFF);
            if (pos < BCAP) temp[(size_t)b * BCAP + pos] = val[k];
        }
    }
}

// ---------------- scan of bucket counts ------------------------------------
__global__ void bscan_kernel(const int* gcount, int* bstart) {
    __shared__ int sh[256];
    int t = threadIdx.x;
    int v = (t < NBUCK) ? gcount[t] : 0;
    sh[t] = v;
    __syncthreads();
    for (int off = 1; off < 256; off <<= 1) {
        int a = (t >= off) ? sh[t - off] : 0;
        __syncthreads();
        sh[t] += a;
        __syncthreads();
    }
    if (t < NBUCK) bstart[t] = sh[t] - v;
    if (t == 0) bstart[NBUCK] = N_EDGES;
}

// ---------------- pass 2: per-bucket CSR build (no global atomics) ---------
__global__ __launch_bounds__(256) void build_kernel(const uint32_t* temp, const int* gcount,
                                                    const int* bstart, int* row_start,
                                                    float* dinv, int* ssort) {
    __shared__ int hist[512];
    __shared__ int sh[256];
    __shared__ int cur[512];
    int b = blockIdx.x;
    int t = threadIdx.x;
    int cnt = min(gcount[b], BCAP);
    int bs = bstart[b];
    const uint32_t* tp = temp + (size_t)b * BCAP;
    hist[t] = 0; hist[t + 256] = 0;
    __syncthreads();
    for (int i = t; i < cnt; i += 256) atomicAdd(&hist[tp[i] & 511], 1);
    __syncthreads();
    int d0 = hist[2 * t], d1 = hist[2 * t + 1];
    int ts = d0 + d1;
    sh[t] = ts;
    __syncthreads();
    for (int off = 1; off < 256; off <<= 1) {
        int a = (t >= off) ? sh[t - off] : 0;
        __syncthreads();
        sh[t] += a;
        __syncthreads();
    }
    int ex = sh[t] - ts;  // exclusive prefix of this thread's 2 nodes
    int node0 = b * 512 + 2 * t;
    cur[2 * t] = ex;
    cur[2 * t + 1] = ex + d0;
    if (node0 < N_NODES) { row_start[node0] = bs + ex;      dinv[node0]     = rsqrtf((float)(d0 + 1)); }
    if (node0 + 1 < N_NODES) { row_start[node0 + 1] = bs + ex + d0; dinv[node0 + 1] = rsqrtf((float)(d1 + 1)); }
    __syncthreads();
    for (int i = t; i < cnt; i += 256) {
        uint32_t v = tp[i];
        int pos = atomicAdd(&cur[v & 511], 1);
        ssort[bs + pos] = (int)(v >> 9);
    }
    if (b == 0 && t == 0) row_start[N_NODES] = N_EDGES;
}

// ---------------- GEMM1: y = dinv * (x @ W1) -------------------------------
#define XS_STRIDE 260
__global__ __launch_bounds__(256) void gemm1_kernel(const float* __restrict__ x,
                                                    const float* __restrict__ W1,
                                                    const float* __restrict__ dinv,
                                                    float* __restrict__ y) {
    __shared__ float xs[32 * XS_STRIDE];
    __shared__ float wl[F_IN * HID];
    int t = threadIdx.x;
    for (int i = t; i < F_IN * HID / 4; i += 256) {
        ((float4*)wl)[i] = ((const float4*)W1)[i];
    }
    int v0 = blockIdx.x * 32;
    for (int c = t; c < 32 * 64; c += 256) {
        int r = c >> 6;
        int j4 = c & 63;
        float4 val = ((const float4*)(x + (size_t)(v0 + r) * F_IN))[j4];
        *((float4*)(xs + r * XS_STRIDE + j4 * 4)) = val;
    }
    __syncthreads();
    int n = t >> 3;          // node within tile (0..31)
    int k0 = (t & 7) * 2;    // feature pair
    const float* xrow = xs + n * XS_STRIDE;
    float a0 = 0.f, a1 = 0.f;
#pragma unroll 4
    for (int j = 0; j < F_IN; j += 4) {
        float4 xv = *((const float4*)(xrow + j));
        float2 w0 = *((const float2*)(wl + (j + 0) * HID + k0));
        float2 w1 = *((const float2*)(wl + (j + 1) * HID + k0));
        float2 w2 = *((const float2*)(wl + (j + 2) * HID + k0));
        float2 w3 = *((const float2*)(wl + (j + 3) * HID + k0));
        a0 += xv.x * w0.x + xv.y * w1.x + xv.z * w2.x + xv.w * w3.x;
        a1 += xv.x * w0.y + xv.y * w1.y + xv.z * w2.y + xv.w * w3.y;
    }
    int v = v0 + n;
    float dv = dinv[v];
    float2 o2;
    o2.x = a0 * dv;
    o2.y = a1 * dv;
    *((float2*)(y + (size_t)v * HID + k0)) = o2;
}

// ---------------- aggregation: h = relu(dinv*(sum_in y + y_self) + b) ------
__global__ __launch_bounds__(256) void agg_kernel(const float* __restrict__ y,
                                                  const float* __restrict__ dinv,
                                                  const float* __restrict__ bias,
                                                  const int* __restrict__ row_start,
                                                  const int* __restrict__ ssort,
                                                  float* __restrict__ hout) {
    int wid = (blockIdx.x * blockDim.x + threadIdx.x) >> 6;  // one wave per node
    int lane = threadIdx.x & 63;
    int v = wid;
    if (v >= N_NODES) return;
    int start = row_start[v];
    int end = row_start[v + 1];
    int q = lane & 3;    // feature quad
    int eg = lane >> 2;  // edge slot (0..15)
    float4 acc = make_float4(0.f, 0.f, 0.f, 0.f);
    for (int base = start; base < end; base += 16) {
        int e = base + eg;
        if (e < end) {
            int s = ssort[e];
            float4 yv = *((const float4*)(y + (size_t)s * HID + q * 4));
            acc.x += yv.x; acc.y += yv.y; acc.z += yv.z; acc.w += yv.w;
        }
    }
#pragma unroll
    for (int m = 4; m < 64; m <<= 1) {
        acc.x += __shfl_xor(acc.x, m);
        acc.y += __shfl_xor(acc.y, m);
        acc.z += __shfl_xor(acc.z, m);
        acc.w += __shfl_xor(acc.w, m);
    }
    if (lane < 4) {
        float4 self = *((const float4*)(y + (size_t)v * HID + lane * 4));
        float dv = dinv[v];
        float4 bv = *((const float4*)(bias + lane * 4));
        float4 r;
        r.x = fmaxf(dv * (acc.x + self.x) + bv.x, 0.f);
        r.y = fmaxf(dv * (acc.y + self.y) + bv.y, 0.f);
        r.z = fmaxf(dv * (acc.z + self.z) + bv.z, 0.f);
        r.w = fmaxf(dv * (acc.w + self.w) + bv.w, 0.f);
        *((float4*)(hout + (size_t)v * HID + lane * 4)) = r;
    }
}

// ---------------- GEMM2: y = dinv * (h @ W2) -------------------------------
__global__ __launch_bounds__(256) void gemm2_kernel(const float* __restrict__ h,
                                                    const float* __restrict__ W2,
                                                    const float* __restrict__ dinv,
                                                    float* __restrict__ y) {
    __shared__ float wl[HID * HID];
    int t = threadIdx.x;
    if (t < 64) ((float4*)wl)[t] = ((const float4*)W2)[t];
    __syncthreads();
    int v = blockIdx.x * blockDim.x + t;
    if (v >= N_NODES) return;
    float hr[16];
    const float4* hp = (const float4*)(h + (size_t)v * HID);
#pragma unroll
    for (int r = 0; r < 4; ++r) {
        float4 hv = hp[r];
        hr[4 * r + 0] = hv.x; hr[4 * r + 1] = hv.y; hr[4 * r + 2] = hv.z; hr[4 * r + 3] = hv.w;
    }
    float acc[16];
#pragma unroll
    for (int k = 0; k < 16; ++k) acc[k] = 0.f;
#pragma unroll
    for (int j = 0; j < 16; ++j) {
        float hv = hr[j];
        const float4* wr = (const float4*)(wl + j * 16);
        float4 w0 = wr[0], w1 = wr[1], w2 = wr[2], w3 = wr[3];
        acc[0] += hv * w0.x;  acc[1] += hv * w0.y;  acc[2] += hv * w0.z;  acc[3] += hv * w0.w;
        acc[4] += hv * w1.x;  acc[5] += hv * w1.y;  acc[6] += hv * w1.z;  acc[7] += hv * w1.w;
        acc[8] += hv * w2.x;  acc[9] += hv * w2.y;  acc[10] += hv * w2.z; acc[11] += hv * w2.w;
        acc[12] += hv * w3.x; acc[13] += hv * w3.y; acc[14] += hv * w3.z; acc[15] += hv * w3.w;
    }
    float dv = dinv[v];
    float4* yp = (float4*)(y + (size_t)v * HID);
#pragma unroll
    for (int r = 0; r < 4; ++r) {
        float4 o;
        o.x = acc[4 * r + 0] * dv; o.y = acc[4 * r + 1] * dv;
        o.z = acc[4 * r + 2] * dv; o.w = acc[4 * r + 3] * dv;
        yp[r] = o;
    }
}

// ---------------- output layer + log_softmax -------------------------------
__global__ __launch_bounds__(256) void out_kernel(const float* __restrict__ h,
                                                  const float* __restrict__ Wout,
                                                  const float* __restrict__ bout,
                                                  float* __restrict__ out) {
    __shared__ float wl[HID * NCLS];
    __shared__ float bl[NCLS];
    int t = threadIdx.x;
    if (t < HID * NCLS) wl[t] = Wout[t];
    if (t < NCLS) bl[t] = bout[t];
    __syncthreads();
    int v = blockIdx.x * blockDim.x + t;
    if (v >= N_NODES) return;
    float hr[16];
    const float4* hp = (const float4*)(h + (size_t)v * HID);
#pragma unroll
    for (int r = 0; r < 4; ++r) {
        float4 hv = hp[r];
        hr[4 * r + 0] = hv.x; hr[4 * r + 1] = hv.y; hr[4 * r + 2] = hv.z; hr[4 * r + 3] = hv.w;
    }
    float lg[NCLS];
#pragma unroll
    for (int c = 0; c < NCLS; ++c) {
        float a = bl[c];
#pragma unroll
        for (int j = 0; j < HID; ++j) a += hr[j] * wl[j * NCLS + c];
        lg[c] = a;
    }
    float m = lg[0];
#pragma unroll
    for (int c = 1; c < NCLS; ++c) m = fmaxf(m, lg[c]);
    float ssum = 0.f;
#pragma unroll
    for (int c = 0; c < NCLS; ++c) ssum += expf(lg[c] - m);
    float lse = m + logf(ssum);
#pragma unroll
    for (int c = 0; c < NCLS; ++c) out[(size_t)v * NCLS + c] = lg[c] - lse;
}

extern "C" void kernel_launch(void* const* d_in, const int* in_sizes, int n_in,
                              void* d_out, int out_size, void* d_ws, size_t ws_size,
                              hipStream_t stream) {
    const float* x    = (const float*)d_in[0];
    const void*  edge = d_in[1];
    const float* W1   = (const float*)d_in[2];
    const float* b1   = (const float*)d_in[3];
    const float* W2   = (const float*)d_in[4];
    const float* b2   = (const float*)d_in[5];
    const float* Wout = (const float*)d_in[6];
    const float* bout = (const float*)d_in[7];
    float* out = (float*)d_out;
    char* ws = (char*)d_ws;

    auto al = [](size_t v) { return (v + 255) & ~(size_t)255; };
    size_t o = 0;
    int*      flag      = (int*)(ws + o);      o = al(o + 4);
    int*      gcount    = (int*)(ws + o);      o = al(o + (size_t)NBUCK * 4);
    int*      bstart    = (int*)(ws + o);      o = al(o + (size_t)(NBUCK + 1) * 4);
    int*      row_start = (int*)(ws + o);      o = al(o + (size_t)(N_NODES + 1) * 4);
    float*    dinv      = (float*)(ws + o);    o = al(o + (size_t)N_NODES * 4);
    uint32_t* temp      = (uint32_t*)(ws + o); o = al(o + (size_t)NBUCK * BCAP * 4);
    int*      ssort     = (int*)(ws + o);      o = al(o + (size_t)N_EDGES * 4);
    float*    ybuf      = (float*)(ws + o);    o = al(o + (size_t)N_NODES * HID * 4);
    float*    hbuf      = (float*)(ws + o);    o = al(o + (size_t)N_NODES * HID * 4);

    hipMemsetAsync(gcount, 0, (size_t)NBUCK * 4, stream);
    detect_kernel<<<1, 256, 0, stream>>>((const uint32_t*)edge, flag);
    bucket_kernel<<<(N_EDGES + EPB - 1) / EPB, 256, 0, stream>>>(edge, flag, gcount, temp);
    bscan_kernel<<<1, 256, 0, stream>>>(gcount, bstart);
    build_kernel<<<NBUCK, 256, 0, stream>>>(temp, gcount, bstart, row_start, dinv, ssort);
    gemm1_kernel<<<N_NODES / 32, 256, 0, stream>>>(x, W1, dinv, ybuf);
    agg_kernel<<<(N_NODES * 64) / 256, 256, 0, stream>>>(ybuf, dinv, b1, row_start, ssort, hbuf);
    gemm2_kernel<<<(N_NODES + 255) / 256, 256, 0, stream>>>(hbuf, W2, dinv, ybuf);
    agg_kernel<<<(N_NODES * 64) / 256, 256, 0, stream>>>(ybuf, dinv, b2, row_start, ssort, hbuf);
    out_kernel<<<(N_NODES + 255) / 256, 256, 0, stream>>>(hbuf, Wout, bout, out);
}